// Round 8
// baseline (209.313 us; speedup 1.0000x reference)
//
#include <hip/hip_runtime.h>

#define HI 1440
#define WI 1920
#define NPIX (HI*WI)
#define EPSF 1e-8f

#define GCOLS 52            // valid output columns per stream
#define NG 37               // ceil(1920/52)
#define SROWS 22            // output rows per strip
#define NPAIR 33            // strip pairs per column group (66 strips, 66*22=1452>=1440)
#define NWAVES (NG*NPAIR)   // 1221 waves, 2 streams each
#define PROWS 35            // raw rows per strip (mult of 7, >= SROWS+13-1)

typedef __fp16 h2 __attribute__((ext_vector_type(2)));

// ---------------- small 3x3 helpers ----------------
__device__ __forceinline__ void mat3mul(const float* A, const float* B, float* C) {
#pragma unroll
  for (int i = 0; i < 3; ++i)
#pragma unroll
    for (int j = 0; j < 3; ++j)
      C[i*3+j] = A[i*3+0]*B[0+j] + A[i*3+1]*B[3+j] + A[i*3+2]*B[6+j];
}

__device__ __forceinline__ void rodrigues_dev(const float* v, float* R) {
  float th = sqrtf(v[0]*v[0] + v[1]*v[1] + v[2]*v[2]) + 1e-12f;
  float kx = v[0]/th, ky = v[1]/th, kz = v[2]/th;
  float st = sinf(th), ct = cosf(th);
  float S[9] = {0.f,-kz,ky, kz,0.f,-kx, -ky,kx,0.f};
  float S2[9];
  mat3mul(S, S, S2);
#pragma unroll
  for (int i = 0; i < 9; ++i) R[i] = st*S[i] + (1.f-ct)*S2[i];
  R[0] += 1.f; R[4] += 1.f; R[8] += 1.f;
}

struct Ctx {
  const float* depth;
  const float* ref;
  const float* tgts;
  float M[24];
  float f;
  int x, ln;
  bool xok;
};

// per-target M[12]: B = K*Rt*R1^T*Kinv (9) and a = K*Rt*(C1-Ct) (3)
__device__ void make_mats(float f, const float* __restrict__ aa,
                          const float* __restrict__ cen, float* m) {
  const float u0 = WI*0.5f - 0.5f;
  const float v0 = HI*0.5f - 0.5f;
  float K[9]  = {f,0.f,u0, 0.f,f,v0, 0.f,0.f,1.f};
  float Ki[9] = {1.f/f,0.f,-u0/f, 0.f,1.f/f,-v0/f, 0.f,0.f,1.f};
  float R1[9]; rodrigues_dev(aa, R1);
  float R1T[9];
#pragma unroll
  for (int i = 0; i < 3; ++i)
#pragma unroll
    for (int j = 0; j < 3; ++j) R1T[i*3+j] = R1[j*3+i];
#pragma unroll
  for (int t = 0; t < 2; ++t) {
    float Rt[9]; rodrigues_dev(aa + 3*(t+1), Rt);
    float A[9]; mat3mul(K, Rt, A);
    float Tm[9]; mat3mul(A, R1T, Tm);
    float B[9]; mat3mul(Tm, Ki, B);
    float Cd[3] = {cen[0]-cen[3*(t+1)+0], cen[1]-cen[3*(t+1)+1], cen[2]-cen[3*(t+1)+2]};
    float* M = m + t*12;
#pragma unroll
    for (int i = 0; i < 9; ++i) M[i] = B[i];
    M[9]  = A[0]*Cd[0]+A[1]*Cd[1]+A[2]*Cd[2];
    M[10] = A[3]*Cd[0]+A[4]*Cd[1]+A[5]*Cd[2];
    M[11] = A[6]*Cd[0]+A[7]*Cd[1]+A[8]*Cd[2];
  }
}

__device__ __forceinline__ float bilerp(const float* __restrict__ img, float px, float py) {
  float x0 = floorf(px), y0 = floorf(py);
  float wx = px - x0, wy = py - y0;
  float x1 = x0 + 1.f, y1 = y0 + 1.f;
  const float xmax = (float)(WI-1), ymax = (float)(HI-1);
  bool bx0 = (x0 >= 0.f) && (x0 <= xmax);
  bool bx1 = (x1 >= 0.f) && (x1 <= xmax);
  bool by0 = (y0 >= 0.f) && (y0 <= ymax);
  bool by1 = (y1 >= 0.f) && (y1 <= ymax);
  float v00 = 0.f, v10 = 0.f, v01 = 0.f, v11 = 0.f;
  if (bx0 && by0) v00 = img[(int)y0*WI + (int)x0];
  if (bx1 && by0) v10 = img[(int)y0*WI + (int)x1];
  if (bx0 && by1) v01 = img[(int)y1*WI + (int)x0];
  if (bx1 && by1) v11 = img[(int)y1*WI + (int)x1];
  return (1.f-wy)*((1.f-wx)*v00 + wx*v10) + wy*((1.f-wx)*v01 + wx*v11);
}

__device__ __forceinline__ float hsum7(float v, int ln) {
  float a = __shfl(v, ln-3, 64), b = __shfl(v, ln-2, 64), c = __shfl(v, ln-1, 64);
  float d = __shfl(v, ln+1, 64), e = __shfl(v, ln+2, 64), g = __shfl(v, ln+3, 64);
  return ((a + b) + (c + v)) + ((d + e) + g);
}

__device__ __forceinline__ h2 hsum7p(h2 v, int ln) {
  int vi = __builtin_bit_cast(int, v);
  h2 a = __builtin_bit_cast(h2, __shfl(vi, ln-3, 64));
  h2 b = __builtin_bit_cast(h2, __shfl(vi, ln-2, 64));
  h2 c = __builtin_bit_cast(h2, __shfl(vi, ln-1, 64));
  h2 d = __builtin_bit_cast(h2, __shfl(vi, ln+1, 64));
  h2 e = __builtin_bit_cast(h2, __shfl(vi, ln+2, 64));
  h2 g = __builtin_bit_cast(h2, __shfl(vi, ln+3, 64));
  return ((a + b) + (c + v)) + ((d + e) + g);
}

__device__ __forceinline__ float loadI(const float* __restrict__ p, int x, int y) {
  return (x >= 0 && x < WI && y >= 0 && y < HI) ? p[y*WI + x] : 0.f;
}

// One independent streaming state: a strip of SROWS output rows.
struct St {
  float dring[7], rring[7];
  h2 wring[7];
  float Hr[7]; h2 Hw[7];
  float Qrr[7]; h2 Q0[7], Q1[7];
  float Sr, S0, S1;
  float Vrr, Vrt0, Vtt0, Vrt1, Vtt1;
  float acc_s, acc_c;
  int R0;

  __device__ __forceinline__ void init(const Ctx& c, int R0_) {
    R0 = R0_;
    const h2 hz = {(__fp16)0.f, (__fp16)0.f};
#pragma unroll
    for (int k = 0; k < 7; ++k) {
      dring[k]=0.f; rring[k]=0.f; wring[k]=hz;
      Hr[k]=0.f; Hw[k]=hz;
      Qrr[k]=0.f; Q0[k]=hz; Q1[k]=hz;
    }
    Sr=S0=S1=0.f;
    Vrr=Vrt0=Vtt0=Vrt1=Vtt1=0.f;
    acc_s=acc_c=0.f;
    dring[6] = loadI(c.depth, c.x, R0-7);
    dring[0] = loadI(c.depth, c.x, R0-6);
  }

  __device__ __forceinline__ void row(const Ctx& c, int j, int ib) {
    const int y = R0 - 6 + ib + j;
    const int x = c.x, ln = c.ln;
    const float f = c.f;
    dring[(j+1)%7] = loadI(c.depth, x, y+1);

    // ---- warp + gather at (x,y), once per pixel ----
    float r = 0.f, w0 = 0.f, w1 = 0.f;
    if (c.xok && y >= 0 && y < HI) {
      const int gidx = y*WI + x;
      r = c.ref[gidx];
      float d  = dring[j%7];
      float dm = (x > 0)    ? c.depth[gidx-1] : 0.f;
      float dp = (x < WI-1) ? c.depth[gidx+1] : 0.f;
      float du = 0.5f*(dp - dm);
      float dv = 0.5f*(dring[(j+1)%7] - dring[(j+6)%7]);
      float fx = (float)x, fy = (float)y;
      float nx = f*du, ny = f*dv;
      float nz = (960.f - fx)*du + (720.f - fy)*dv - d;
      float nn = sqrtf(nx*nx + ny*ny + nz*nz) + EPSF;
      float wsc = 1.f/(nn*(d + EPSF));
      float px = (fx - 959.5f)/f, py = (fy - 719.5f)/f;
      float sv = (nx*px + ny*py + nz)*wsc;
      {
        float a0 = c.M[0]*fx + c.M[1]*fy + c.M[2] + c.M[9]*sv;
        float a1 = c.M[3]*fx + c.M[4]*fy + c.M[5] + c.M[10]*sv;
        float a2 = c.M[6]*fx + c.M[7]*fy + c.M[8] + c.M[11]*sv;
        float iz = 1.f/(a2 + EPSF);
        w0 = bilerp(c.tgts, a0*iz, a1*iz);
      }
      {
        float a0 = c.M[12]*fx + c.M[13]*fy + c.M[14] + c.M[21]*sv;
        float a1 = c.M[15]*fx + c.M[16]*fy + c.M[17] + c.M[22]*sv;
        float a2 = c.M[18]*fx + c.M[19]*fy + c.M[20] + c.M[23]*sv;
        float iz = 1.f/(a2 + EPSF);
        w1 = bilerp(c.tgts + NPIX, a0*iz, a1*iz);
      }
    }
    rring[j%7] = r;
    h2 wp = __builtin_amdgcn_cvt_pkrtz(w0, w1);
    wring[j%7] = wp;

    // ---- horizontal 7-sums of raw planes ----
    float hr = hsum7(r, ln);
    h2 hw = hsum7p(wp, ln);

    // ---- vertical running box sums; box complete at yc = y-3 ----
    Sr += hr; S0 += (float)hw.x; S1 += (float)hw.y;
    const float Br = Sr, B0 = S0, B1 = S1;
    h2 hwold = Hw[(j+1)%7];
    Sr -= Hr[(j+1)%7]; S0 -= (float)hwold.x; S1 -= (float)hwold.y;
    Hr[j%7] = hr; Hw[j%7] = hw;

    // ---- centered values at row yc ----
    const int yc = y - 3;
    float cr = 0.f, c0 = 0.f, c1 = 0.f;
    if (c.xok && yc >= 0 && yc < HI) {
      h2 wc = wring[(j+4)%7];
      cr = rring[(j+4)%7] - Br*(1.f/49.f);
      c0 = (float)wc.x - B0*(1.f/49.f);
      c1 = (float)wc.y - B1*(1.f/49.f);
    }

    // ---- product horizontal 7-sums (fp16-packed, quantize-then-accumulate) ----
    float prr = hsum7(cr*cr, ln);
    h2 q0 = hsum7p(__builtin_amdgcn_cvt_pkrtz(cr*c0, c0*c0), ln);
    h2 q1 = hsum7p(__builtin_amdgcn_cvt_pkrtz(cr*c1, c1*c1), ln);

    // ---- vertical running window sums; window complete at yo = y-6 ----
    Vrr += prr;
    Vrt0 += (float)q0.x; Vtt0 += (float)q0.y;
    Vrt1 += (float)q1.x; Vtt1 += (float)q1.y;

    const int yo = y - 6;
    if (yo >= R0 && yo < R0 + SROWS && yo < HI && ln >= 6 && ln <= 57 && x < WI) {
      const int mb = __builtin_bit_cast(int, wring[(j+1)%7]);  // raw w at row yo
      const float inv49 = 1.f/49.f;
      float vr = Vrr*inv49;
      if (mb & 0xffff) {
        float zm = ((float)Vrt0*inv49) * rsqrtf(vr*(Vtt0*inv49) + EPSF);
        acc_s += zm; acc_c += 1.f;
      }
      if (((unsigned)mb >> 16) != 0u) {
        float zm = ((float)Vrt1*inv49) * rsqrtf(vr*(Vtt1*inv49) + EPSF);
        acc_s += zm; acc_c += 1.f;
      }
    }

    h2 q0old = Q0[(j+5)%7], q1old = Q1[(j+5)%7];
    Vrr -= Qrr[(j+5)%7];
    Vrt0 -= (float)q0old.x; Vtt0 -= (float)q0old.y;
    Vrt1 -= (float)q1old.x; Vtt1 -= (float)q1old.y;
    Qrr[(j+4)%7] = prr; Q0[(j+4)%7] = q0; Q1[(j+4)%7] = q1;
  }
};

// Dual-stream wave kernel: one wave (64-thread block) owns two vertically
// adjacent strips of the same column group; rows interleaved A,B for ILP.
__global__ __launch_bounds__(64) void k_stream(const float* __restrict__ focal,
                                               const float* __restrict__ aa,
                                               const float* __restrict__ cen,
                                               const float* __restrict__ depth,
                                               const float* __restrict__ ref,
                                               const float* __restrict__ tgts,
                                               float* __restrict__ partials) {
  const int wid = blockIdx.x;
  const int ln = threadIdx.x;
  const int g = wid / NPAIR, m = wid - g*NPAIR;

  Ctx c;
  c.depth = depth; c.ref = ref; c.tgts = tgts;
  c.f = focal[0];
  c.ln = ln;
  c.x = g*GCOLS - 6 + ln;
  c.xok = (c.x >= 0) && (c.x < WI);
  make_mats(c.f, aa, cen, c.M);

  St A, B;
  A.init(c, (2*m)*SROWS);
  B.init(c, (2*m+1)*SROWS);

  for (int ib = 0; ib < PROWS; ib += 7) {
#pragma unroll
    for (int j = 0; j < 7; ++j) {
      A.row(c, j, ib);
      B.row(c, j, ib);
    }
  }

  float s = A.acc_s + B.acc_s;
  float cc = A.acc_c + B.acc_c;
#pragma unroll
  for (int off = 32; off > 0; off >>= 1) {
    s  += __shfl_down(s, off, 64);
    cc += __shfl_down(cc, off, 64);
  }
  if (ln == 0) { partials[2*wid] = s; partials[2*wid+1] = cc; }
}

__global__ __launch_bounds__(256) void k_final(const float* __restrict__ partials, int nb,
                                               float* __restrict__ out) {
  float s = 0.f, c = 0.f;
  for (int i = threadIdx.x; i < nb; i += 256) {
    s += partials[2*i];
    c += partials[2*i+1];
  }
#pragma unroll
  for (int off = 32; off > 0; off >>= 1) {
    s += __shfl_down(s, off, 64);
    c += __shfl_down(c, off, 64);
  }
  __shared__ float red[8];
  int tid = threadIdx.x;
  if ((tid & 63) == 0) { red[(tid>>6)*2] = s; red[(tid>>6)*2+1] = c; }
  __syncthreads();
  if (tid == 0) {
    float S = red[0]+red[2]+red[4]+red[6];
    float C = red[1]+red[3]+red[5]+red[7];
    float mean = S / fmaxf(C, 1.f);
    out[0] = (C > 0.f) ? 0.5f*(1.f - mean) : 0.f;
  }
}

extern "C" void kernel_launch(void* const* d_in, const int* in_sizes, int n_in,
                              void* d_out, int out_size, void* d_ws, size_t ws_size,
                              hipStream_t stream) {
  const float* focal  = (const float*)d_in[0];
  const float* aa     = (const float*)d_in[1];
  const float* cen    = (const float*)d_in[2];
  const float* ref    = (const float*)d_in[3];
  const float* depth  = (const float*)d_in[4];
  const float* tgts   = (const float*)d_in[5];
  float* out = (float*)d_out;

  float* partials = (float*)d_ws;     // 2 * NWAVES

  k_stream<<<NWAVES, 64, 0, stream>>>(focal, aa, cen, depth, ref, tgts, partials);
  k_final<<<1, 256, 0, stream>>>(partials, NWAVES, out);
}

// Round 9
// 174.673 us; speedup vs baseline: 1.1983x; 1.1983x over previous
//
#include <hip/hip_runtime.h>

#define HI 1440
#define WI 1920
#define NPIX (HI*WI)
#define EPSF 1e-8f

#define GCOLS 52            // valid output columns per wave
#define NG 37               // ceil(1920/52)
#define SROWS 22            // output rows per strip
#define NS 66               // ceil(1440/22)
#define NWAVES (NG*NS)      // 2442
#define NITER 35            // pipeline iters: issue rows R0-6..R0+27 (34), consume shifted by 1

typedef __fp16 h2 __attribute__((ext_vector_type(2)));

// ---------------- small 3x3 helpers ----------------
__device__ __forceinline__ void mat3mul(const float* A, const float* B, float* C) {
#pragma unroll
  for (int i = 0; i < 3; ++i)
#pragma unroll
    for (int j = 0; j < 3; ++j)
      C[i*3+j] = A[i*3+0]*B[0+j] + A[i*3+1]*B[3+j] + A[i*3+2]*B[6+j];
}

__device__ __forceinline__ void rodrigues_dev(const float* v, float* R) {
  float th = sqrtf(v[0]*v[0] + v[1]*v[1] + v[2]*v[2]) + 1e-12f;
  float kx = v[0]/th, ky = v[1]/th, kz = v[2]/th;
  float st = sinf(th), ct = cosf(th);
  float S[9] = {0.f,-kz,ky, kz,0.f,-kx, -ky,kx,0.f};
  float S2[9];
  mat3mul(S, S, S2);
#pragma unroll
  for (int i = 0; i < 9; ++i) R[i] = st*S[i] + (1.f-ct)*S2[i];
  R[0] += 1.f; R[4] += 1.f; R[8] += 1.f;
}

// per-target M[12]: B = K*Rt*R1^T*Kinv (9) and a = K*Rt*(C1-Ct) (3)
__device__ void make_mats(float f, const float* __restrict__ aa,
                          const float* __restrict__ cen, float* m) {
  const float u0 = WI*0.5f - 0.5f;
  const float v0 = HI*0.5f - 0.5f;
  float K[9]  = {f,0.f,u0, 0.f,f,v0, 0.f,0.f,1.f};
  float Ki[9] = {1.f/f,0.f,-u0/f, 0.f,1.f/f,-v0/f, 0.f,0.f,1.f};
  float R1[9]; rodrigues_dev(aa, R1);
  float R1T[9];
#pragma unroll
  for (int i = 0; i < 3; ++i)
#pragma unroll
    for (int j = 0; j < 3; ++j) R1T[i*3+j] = R1[j*3+i];
#pragma unroll
  for (int t = 0; t < 2; ++t) {
    float Rt[9]; rodrigues_dev(aa + 3*(t+1), Rt);
    float A[9]; mat3mul(K, Rt, A);
    float Tm[9]; mat3mul(A, R1T, Tm);
    float B[9]; mat3mul(Tm, Ki, B);
    float Cd[3] = {cen[0]-cen[3*(t+1)+0], cen[1]-cen[3*(t+1)+1], cen[2]-cen[3*(t+1)+2]};
    float* M = m + t*12;
#pragma unroll
    for (int i = 0; i < 9; ++i) M[i] = B[i];
    M[9]  = A[0]*Cd[0]+A[1]*Cd[1]+A[2]*Cd[2];
    M[10] = A[3]*Cd[0]+A[4]*Cd[1]+A[5]*Cd[2];
    M[11] = A[6]*Cd[0]+A[7]*Cd[1]+A[8]*Cd[2];
  }
}

__device__ __forceinline__ float hsum7(float v, int ln) {
  float a = __shfl(v, ln-3, 64), b = __shfl(v, ln-2, 64), c = __shfl(v, ln-1, 64);
  float d = __shfl(v, ln+1, 64), e = __shfl(v, ln+2, 64), g = __shfl(v, ln+3, 64);
  return ((a + b) + (c + v)) + ((d + e) + g);
}

__device__ __forceinline__ h2 hsum7p(h2 v, int ln) {
  int vi = __builtin_bit_cast(int, v);
  h2 a = __builtin_bit_cast(h2, __shfl(vi, ln-3, 64));
  h2 b = __builtin_bit_cast(h2, __shfl(vi, ln-2, 64));
  h2 c = __builtin_bit_cast(h2, __shfl(vi, ln-1, 64));
  h2 d = __builtin_bit_cast(h2, __shfl(vi, ln+1, 64));
  h2 e = __builtin_bit_cast(h2, __shfl(vi, ln+2, 64));
  h2 g = __builtin_bit_cast(h2, __shfl(vi, ln+3, 64));
  return ((a + b) + (c + v)) + ((d + e) + g);
}

__device__ __forceinline__ float loadI(const float* __restrict__ p, int x, int y) {
  return (x >= 0 && x < WI && y >= 0 && y < HI) ? p[y*WI + x] : 0.f;
}

// issue one target's 4 tap loads + validity-folded weights
__device__ __forceinline__ void issue_tap(const float* __restrict__ img,
                                          const float* __restrict__ M,
                                          float sv, float fx, float fy, bool vrow,
                                          float* T, float* W) {
  float a0 = M[0]*fx + M[1]*fy + M[2] + M[9]*sv;
  float a1 = M[3]*fx + M[4]*fy + M[5] + M[10]*sv;
  float a2 = M[6]*fx + M[7]*fy + M[8] + M[11]*sv;
  float iz = 1.f/(a2 + EPSF);
  float px = a0*iz, py = a1*iz;
  float x0f = floorf(px), y0f = floorf(py);
  float wx = px - x0f, wy = py - y0f;
  bool bx0 = (x0f >= 0.f) && (x0f <= (float)(WI-1));
  bool bx1 = (x0f >= -1.f) && (x0f <= (float)(WI-2));
  bool by0 = (y0f >= 0.f) && (y0f <= (float)(HI-1));
  bool by1 = (y0f >= -1.f) && (y0f <= (float)(HI-2));
  int xi0 = (int)fminf(fmaxf(x0f,       0.f), (float)(WI-1));
  int xi1 = (int)fminf(fmaxf(x0f + 1.f, 0.f), (float)(WI-1));
  int yi0 = (int)fminf(fmaxf(y0f,       0.f), (float)(HI-1));
  int yi1 = (int)fminf(fmaxf(y0f + 1.f, 0.f), (float)(HI-1));
  int r0 = yi0*WI, r1 = yi1*WI;
  T[0] = img[r0 + xi0];
  T[1] = img[r0 + xi1];
  T[2] = img[r1 + xi0];
  T[3] = img[r1 + xi1];
  float u = 1.f - wx, v = 1.f - wy;
  W[0] = (vrow && bx0 && by0) ? v*u  : 0.f;
  W[1] = (vrow && bx1 && by0) ? v*wx : 0.f;
  W[2] = (vrow && bx0 && by1) ? wy*u : 0.f;
  W[3] = (vrow && bx1 && by1) ? wy*wx : 0.f;
}

// Fused wave-streaming kernel with 1-row software pipeline:
// iteration i: ISSUE(row y = R0-6+i): depth/ref/tap loads + weights;
//              CONSUME(row y-1): finish bilerp from prev taps, hsums, rings.
__global__ __launch_bounds__(256) void k_stream(const float* __restrict__ focal,
                                                const float* __restrict__ aa,
                                                const float* __restrict__ cen,
                                                const float* __restrict__ depth,
                                                const float* __restrict__ ref,
                                                const float* __restrict__ tgts,
                                                float* __restrict__ partials) {
  const int wid = blockIdx.x*4 + (threadIdx.x >> 6);
  if (wid >= NWAVES) return;
  const int ln = threadIdx.x & 63;
  const int g = wid % NG, st = wid / NG;
  const int R0 = st * SROWS;
  const int x = g*GCOLS - 6 + ln;
  const bool xok = (x >= 0) && (x < WI);
  const int gxL = g*GCOLS - 7, gxR = g*GCOLS + 58;

  float f = focal[0];
  float M[24];
  make_mats(f, aa, cen, M);
  // wave-uniform -> SGPRs
#pragma unroll
  for (int i2 = 0; i2 < 24; ++i2)
    M[i2] = __builtin_bit_cast(float, __builtin_amdgcn_readfirstlane(__builtin_bit_cast(int, M[i2])));
  f = __builtin_bit_cast(float, __builtin_amdgcn_readfirstlane(__builtin_bit_cast(int, f)));

  // rings (mod-7, static indices under unroll)
  float rring[7];
  h2 wring[7];
  float Hr[7], H0[7], H1[7];
  float Qrr[7], Qrt0[7], Qtt0[7], Qrt1[7], Qtt1[7];
  const h2 hz = {(__fp16)0.f, (__fp16)0.f};
#pragma unroll
  for (int k = 0; k < 7; ++k) {
    rring[k]=0.f; wring[k]=hz;
    Hr[k]=0.f; H0[k]=0.f; H1[k]=0.f;
    Qrr[k]=0.f; Qrt0[k]=0.f; Qtt0[k]=0.f; Qrt1[k]=0.f; Qtt1[k]=0.f;
  }
  float Sr=0.f, S0=0.f, S1=0.f;
  float Vrr=0.f, Vrt0=0.f, Vtt0=0.f, Vrt1=0.f, Vtt1=0.f;
  float acc_s=0.f, acc_c=0.f;

  // pipeline state (consume side)
  float r_pend = 0.f;
  float T0[4]={0,0,0,0}, W0[4]={0,0,0,0}, T1[4]={0,0,0,0}, W1[4]={0,0,0,0};

  // depth shift regs: at issue(y): d_m1=d(y-1), d_0=d(y), d_p1=d(y+1)
  float d_m1 = loadI(depth, x, R0-7);
  float d_0  = loadI(depth, x, R0-6);
  float d_p1 = loadI(depth, x, R0-5);
  float eL = loadI(depth, gxL, R0-6);
  float eR = loadI(depth, gxR, R0-6);

  for (int ib = 0; ib < NITER; ib += 7) {
#pragma unroll
    for (int jj = 0; jj < 7; ++jj) {
      const int i = ib + jj;
      const int y = R0 - 6 + i;

      // ---------------- ISSUE(y) ----------------
      float nd=0.f, neL=0.f, neR=0.f, nr=0.f;
      float nT0[4]={0,0,0,0}, nW0[4]={0,0,0,0}, nT1[4]={0,0,0,0}, nW1[4]={0,0,0,0};
      if (i < NITER-1) {
        nd  = loadI(depth, x, y+2);
        neL = loadI(depth, gxL, y+1);
        neR = loadI(depth, gxR, y+1);
        nr  = loadI(ref, x, y);
        const bool vrow = xok && (y >= 0) && (y < HI);
        float dmv = __shfl(d_0, ln-1, 64); dmv = (ln == 0)  ? eL : dmv;
        float dpv = __shfl(d_0, ln+1, 64); dpv = (ln == 63) ? eR : dpv;
        float du = 0.5f*(dpv - dmv);
        float dv = 0.5f*(d_p1 - d_m1);
        float fx = (float)x, fy = (float)y;
        float nx = f*du, ny = f*dv;
        float nz = (960.f - fx)*du + (720.f - fy)*dv - d_0;
        float nn = sqrtf(nx*nx + ny*ny + nz*nz) + EPSF;
        float wsc = 1.f/(nn*(d_0 + EPSF));
        float px_ = (fx - 959.5f)/f, py_ = (fy - 719.5f)/f;
        float sv = (nx*px_ + ny*py_ + nz)*wsc;
        issue_tap(tgts,        M,      sv, fx, fy, vrow, nT0, nW0);
        issue_tap(tgts + NPIX, M + 12, sv, fx, fy, vrow, nT1, nW1);
      }

      // ---------------- CONSUME(row ym = y-1) ----------------
      {
        float w0 = W0[0]*T0[0] + W0[1]*T0[1] + W0[2]*T0[2] + W0[3]*T0[3];
        float w1 = W1[0]*T1[0] + W1[1]*T1[1] + W1[2]*T1[2] + W1[3]*T1[3];
        float r = r_pend;
        const int ym = y - 1;
        h2 wp = __builtin_amdgcn_cvt_pkrtz(w0, w1);
        rring[jj] = r; wring[jj] = wp;

        float hr = hsum7(r, ln);
        h2 hw = hsum7p(wp, ln);
        float h0 = (float)hw.x, h1 = (float)hw.y;

        Sr += hr; S0 += h0; S1 += h1;
        const float Br = Sr, B0 = S0, B1 = S1;
        Sr -= Hr[(jj+1)%7]; S0 -= H0[(jj+1)%7]; S1 -= H1[(jj+1)%7];
        Hr[jj] = hr; H0[jj] = h0; H1[jj] = h1;

        const int yc = ym - 3;
        float cr = 0.f, c0 = 0.f, c1 = 0.f;
        if (xok && yc >= 0 && yc < HI) {
          h2 wc = wring[(jj+4)%7];
          cr = rring[(jj+4)%7] - Br*(1.f/49.f);
          c0 = (float)wc.x - B0*(1.f/49.f);
          c1 = (float)wc.y - B1*(1.f/49.f);
        }

        float prr = hsum7(cr*cr, ln);
        h2 q0 = hsum7p(__builtin_amdgcn_cvt_pkrtz(cr*c0, c0*c0), ln);
        h2 q1 = hsum7p(__builtin_amdgcn_cvt_pkrtz(cr*c1, c1*c1), ln);
        float hrt0 = (float)q0.x, htt0 = (float)q0.y;
        float hrt1 = (float)q1.x, htt1 = (float)q1.y;

        Vrr += prr; Vrt0 += hrt0; Vtt0 += htt0; Vrt1 += hrt1; Vtt1 += htt1;

        const int yo = ym - 6;
        if (yo >= R0 && yo < R0 + SROWS && yo < HI && ln >= 6 && ln <= 57 && x < WI) {
          const int mb = __builtin_bit_cast(int, wring[(jj+1)%7]);  // raw w at row yo
          const float inv49 = 1.f/49.f;
          float vr = Vrr*inv49;
          if (mb & 0xffff) {
            float zm = (Vrt0*inv49) * rsqrtf(vr*(Vtt0*inv49) + EPSF);
            acc_s += zm; acc_c += 1.f;
          }
          if (((unsigned)mb >> 16) != 0u) {
            float zm = (Vrt1*inv49) * rsqrtf(vr*(Vtt1*inv49) + EPSF);
            acc_s += zm; acc_c += 1.f;
          }
        }

        Vrr -= Qrr[(jj+5)%7]; Vrt0 -= Qrt0[(jj+5)%7]; Vtt0 -= Qtt0[(jj+5)%7];
        Vrt1 -= Qrt1[(jj+5)%7]; Vtt1 -= Qtt1[(jj+5)%7];
        Qrr[(jj+4)%7] = prr; Qrt0[(jj+4)%7] = hrt0; Qtt0[(jj+4)%7] = htt0;
        Qrt1[(jj+4)%7] = hrt1; Qtt1[(jj+4)%7] = htt1;
      }

      // ---------------- shift pipeline ----------------
      r_pend = nr;
#pragma unroll
      for (int k = 0; k < 4; ++k) {
        T0[k] = nT0[k]; W0[k] = nW0[k];
        T1[k] = nT1[k]; W1[k] = nW1[k];
      }
      d_m1 = d_0; d_0 = d_p1; d_p1 = nd;
      eL = neL; eR = neR;
    }
  }

  // ---- wave reduce, one partial pair per wave (distinct addresses) ----
#pragma unroll
  for (int off = 32; off > 0; off >>= 1) {
    acc_s += __shfl_down(acc_s, off, 64);
    acc_c += __shfl_down(acc_c, off, 64);
  }
  if (ln == 0) { partials[2*wid] = acc_s; partials[2*wid+1] = acc_c; }
}

__global__ __launch_bounds__(256) void k_final(const float* __restrict__ partials, int nb,
                                               float* __restrict__ out) {
  float s = 0.f, c = 0.f;
  for (int i = threadIdx.x; i < nb; i += 256) {
    s += partials[2*i];
    c += partials[2*i+1];
  }
#pragma unroll
  for (int off = 32; off > 0; off >>= 1) {
    s += __shfl_down(s, off, 64);
    c += __shfl_down(c, off, 64);
  }
  __shared__ float red[8];
  int tid = threadIdx.x;
  if ((tid & 63) == 0) { red[(tid>>6)*2] = s; red[(tid>>6)*2+1] = c; }
  __syncthreads();
  if (tid == 0) {
    float S = red[0]+red[2]+red[4]+red[6];
    float C = red[1]+red[3]+red[5]+red[7];
    float mean = S / fmaxf(C, 1.f);
    out[0] = (C > 0.f) ? 0.5f*(1.f - mean) : 0.f;
  }
}

extern "C" void kernel_launch(void* const* d_in, const int* in_sizes, int n_in,
                              void* d_out, int out_size, void* d_ws, size_t ws_size,
                              hipStream_t stream) {
  const float* focal  = (const float*)d_in[0];
  const float* aa     = (const float*)d_in[1];
  const float* cen    = (const float*)d_in[2];
  const float* ref    = (const float*)d_in[3];
  const float* depth  = (const float*)d_in[4];
  const float* tgts   = (const float*)d_in[5];
  float* out = (float*)d_out;

  float* partials = (float*)d_ws;     // 2 * NWAVES

  k_stream<<<(NWAVES + 3)/4, 256, 0, stream>>>(focal, aa, cen, depth, ref, tgts, partials);
  k_final<<<1, 256, 0, stream>>>(partials, NWAVES, out);
}